// Round 2
// baseline (291.420 us; speedup 1.0000x reference)
//
#include <hip/hip_runtime.h>
#include <stdint.h>

// NeiAttention: B=512, N=32, S=16, EF=64, NF=D=128, K=192. Tiles = B*N = 16384.
// One (b,n) tile per WAVE, zero barriers in the main loop:
//  - W^T bf16 B-fragments staged once to shared LDS (48 KB), 1 barrier at start
//  - per-wave private A-tile staging (6 KB LDS slice), intra-wave lgkm ordering only
//  - 48x mfma_f32_16x16x32_bf16 per tile, softmax epilogue in registers via shfl_xor

typedef __attribute__((ext_vector_type(8))) short short8;
typedef __attribute__((ext_vector_type(4))) float float4_t;
typedef __attribute__((ext_vector_type(4))) unsigned short ushort4_t;

#define NBLK 512
#define ITERS 8   // 512 blocks * 4 waves * 8 tiles = 16384

__device__ __forceinline__ unsigned short f2bf(float f) {
    uint32_t u = __float_as_uint(f);
    u += 0x7fffu + ((u >> 16) & 1u);   // RNE
    return (unsigned short)(u >> 16);
}

// A-fragment LDS offset (ushort units) for element (s, k):
// kstep q=k/32, owner lane = ((k%32)/8)*16 + s, j = k%8.
__device__ __forceinline__ int aoff(int s, int kc) {
    return (((kc >> 5) * 64) + (((kc & 31) >> 3) * 16) + s) * 8 + (kc & 7);
}

__global__ __launch_bounds__(256, 2) void nei_attn_kernel(
    const float* __restrict__ x,
    const float* __restrict__ rel,
    const float* __restrict__ node,
    const float* __restrict__ W,
    const float* __restrict__ bias,
    float* __restrict__ out)
{
    __shared__ __align__(16) unsigned short lds_w[48 * 64 * 8]; // 48 KB: B-frags, all 8 ct x 6 q
    __shared__ __align__(16) unsigned short lds_a[4][6 * 64 * 8]; // 6 KB per wave
    __shared__ __align__(16) float lds_x[4][128];

    const int t    = threadIdx.x;
    const int lane = t & 63;
    const int wv   = t >> 6;
    const int l15  = lane & 15;
    const int quad = lane >> 4;

    // ---- stage W^T as bf16 B-fragments into shared LDS (once) ----
    // chunk ch = ct*6+q; B-frag lane ln holds W[ct*16 + (ln&15)][q*32 + (ln>>4)*8 + j]
    #pragma unroll
    for (int c = 0; c < 12; ++c) {
        const int ch = c * 4 + wv;
        const int ct = ch / 6, q = ch - ct * 6;
        const float* p = W + (ct * 16 + l15) * 192 + q * 32 + quad * 8;
        float4_t w0 = *(const float4_t*)p;
        float4_t w1 = *(const float4_t*)(p + 4);
        short8 f;
        f[0] = (short)f2bf(w0.x); f[1] = (short)f2bf(w0.y);
        f[2] = (short)f2bf(w0.z); f[3] = (short)f2bf(w0.w);
        f[4] = (short)f2bf(w1.x); f[5] = (short)f2bf(w1.y);
        f[6] = (short)f2bf(w1.z); f[7] = (short)f2bf(w1.w);
        *(short8*)&lds_w[(ch * 64 + lane) * 8] = f;
    }
    float bias_l[8];
    #pragma unroll
    for (int ct = 0; ct < 8; ++ct) bias_l[ct] = bias[ct * 16 + l15];

    // staging LDS offsets (loop-invariant). s = l15; f4col = quad + 4c.
    int aor[4], aon[8];
    #pragma unroll
    for (int c = 0; c < 4; ++c) aor[c] = aoff(l15, (quad + 4 * c) * 4);
    #pragma unroll
    for (int c = 0; c < 8; ++c) aon[c] = aoff(l15, 64 + (quad + 4 * c) * 4);

    __syncthreads();   // the ONLY barrier

    int tile = (blockIdx.x * 4 + wv) * ITERS;

    // ---- prefetch tile 0 ----
    float4_t pr[4], pn[8], px = (float4_t){0.f, 0.f, 0.f, 0.f};
    {
        const float4_t* rb = (const float4_t*)(rel  + (size_t)tile * 1024);
        const float4_t* nb = (const float4_t*)(node + (size_t)tile * 2048);
        #pragma unroll
        for (int c = 0; c < 4; ++c) pr[c] = rb[l15 * 16 + quad + 4 * c];
        #pragma unroll
        for (int c = 0; c < 8; ++c) pn[c] = nb[l15 * 32 + quad + 4 * c];
        if (lane < 32) px = ((const float4_t*)(x + (size_t)tile * 128))[lane];
    }

    for (int it = 0; it < ITERS; ++it) {
        // ---- stage prefetched tile -> private LDS (bf16 A-frag packed) ----
        #pragma unroll
        for (int c = 0; c < 4; ++c) {
            ushort4_t u;
            u[0] = f2bf(pr[c].x); u[1] = f2bf(pr[c].y);
            u[2] = f2bf(pr[c].z); u[3] = f2bf(pr[c].w);
            *(ushort4_t*)&lds_a[wv][aor[c]] = u;
        }
        #pragma unroll
        for (int c = 0; c < 8; ++c) {
            ushort4_t u;
            u[0] = f2bf(pn[c].x); u[1] = f2bf(pn[c].y);
            u[2] = f2bf(pn[c].z); u[3] = f2bf(pn[c].w);
            *(ushort4_t*)&lds_a[wv][aon[c]] = u;
        }
        if (lane < 32) *(float4_t*)&lds_x[wv][lane * 4] = px;

        // ---- prefetch next tile (no barriers ahead -> stays in flight) ----
        if (it + 1 < ITERS) {
            const int nt = tile + 1;
            const float4_t* rb = (const float4_t*)(rel  + (size_t)nt * 1024);
            const float4_t* nb = (const float4_t*)(node + (size_t)nt * 2048);
            #pragma unroll
            for (int c = 0; c < 4; ++c) pr[c] = rb[l15 * 16 + quad + 4 * c];
            #pragma unroll
            for (int c = 0; c < 8; ++c) pn[c] = nb[l15 * 32 + quad + 4 * c];
            if (lane < 32) px = ((const float4_t*)(x + (size_t)nt * 128))[lane];
        }

        // ---- projection: v(16x128) = feat(16x192) @ W^T ----
        short8 areg[6];
        #pragma unroll
        for (int q = 0; q < 6; ++q)
            areg[q] = *(const short8*)&lds_a[wv][(q * 64 + lane) * 8];

        float4_t acc[8];
        #pragma unroll
        for (int ct = 0; ct < 8; ++ct) acc[ct] = (float4_t){0.f, 0.f, 0.f, 0.f};
        #pragma unroll
        for (int ct = 0; ct < 8; ++ct) {
            #pragma unroll
            for (int q = 0; q < 6; ++q) {
                short8 b = *(const short8*)&lds_w[((ct * 6 + q) * 64 + lane) * 8];
                acc[ct] = __builtin_amdgcn_mfma_f32_16x16x32_bf16(areg[q], b, acc[ct], 0, 0, 0);
            }
        }
        #pragma unroll
        for (int ct = 0; ct < 8; ++ct) {
            acc[ct][0] += bias_l[ct]; acc[ct][1] += bias_l[ct];
            acc[ct][2] += bias_l[ct]; acc[ct][3] += bias_l[ct];
        }

        // ---- attention epilogue, all in registers ----
        // lane holds v[s = 4*quad + r][d = 16*ct + l15], r=0..3, ct=0..7
        float xr[8];
        #pragma unroll
        for (int ct = 0; ct < 8; ++ct) xr[ct] = lds_x[wv][ct * 16 + l15];

        float p0 = 0.f, p1 = 0.f, p2 = 0.f, p3 = 0.f;
        #pragma unroll
        for (int ct = 0; ct < 8; ++ct) {
            p0 += xr[ct] * acc[ct][0]; p1 += xr[ct] * acc[ct][1];
            p2 += xr[ct] * acc[ct][2]; p3 += xr[ct] * acc[ct][3];
        }
        // reduce over the 16 lanes sharing a quad (same rows)
        #pragma unroll
        for (int m = 1; m <= 8; m <<= 1) {
            p0 += __shfl_xor(p0, m); p1 += __shfl_xor(p1, m);
            p2 += __shfl_xor(p2, m); p3 += __shfl_xor(p3, m);
        }
        const float norm = 0.08838834764831845f;   // 1/sqrt(128)
        p0 *= norm; p1 *= norm; p2 *= norm; p3 *= norm;
        // softmax over the 16 rows: cross-quad max & sum via xor 16/32
        float mx = fmaxf(fmaxf(p0, p1), fmaxf(p2, p3));
        mx = fmaxf(mx, __shfl_xor(mx, 16));
        mx = fmaxf(mx, __shfl_xor(mx, 32));
        float e0 = __expf(p0 - mx), e1 = __expf(p1 - mx);
        float e2 = __expf(p2 - mx), e3 = __expf(p3 - mx);
        float den = e0 + e1 + e2 + e3;
        den += __shfl_xor(den, 16);
        den += __shfl_xor(den, 32);
        const float inv = 1.0f / den;
        const float w0 = e0 * inv, w1 = e1 * inv, w2 = e2 * inv, w3 = e3 * inv;

        // out[d] = sum_s w[s] * v[s][d]; partial over own 4 rows, reduce across quads
        float s0 = 0.f, s1 = 0.f;
        #pragma unroll
        for (int ct = 0; ct < 8; ++ct) {
            float v = w0 * acc[ct][0] + w1 * acc[ct][1]
                    + w2 * acc[ct][2] + w3 * acc[ct][3];
            v += __shfl_xor(v, 16);
            v += __shfl_xor(v, 32);
            // keep only the two columns this quad will store (no dynamic indexing)
            if ((ct >> 1) == quad) { if (ct & 1) s1 = v; else s0 = v; }
        }
        float* ob = out + (size_t)tile * 128;
        ob[quad * 32 + l15]      = s0;
        ob[quad * 32 + 16 + l15] = s1;

        ++tile;
    }
}

extern "C" void kernel_launch(void* const* d_in, const int* in_sizes, int n_in,
                              void* d_out, int out_size, void* d_ws, size_t ws_size,
                              hipStream_t stream) {
    const float* x    = (const float*)d_in[0];
    const float* rel  = (const float*)d_in[1];
    const float* node = (const float*)d_in[2];
    const float* W    = (const float*)d_in[3];
    const float* bias = (const float*)d_in[4];
    float* out = (float*)d_out;
    hipLaunchKernelGGL(nei_attn_kernel, dim3(NBLK), dim3(256), 0, stream,
                       x, rel, node, W, bias, out);
}